// Round 10
// baseline (162.004 us; speedup 1.0000x reference)
//
#include <hip/hip_runtime.h>
#include <hip/hip_bf16.h>

#define NPTS 262144
#define DDIM 64
#define KCB  1024
#define CHUNK 128            // codebook rows per staged chunk (32 KB image)
#define NCHUNK (KCB / CHUNK) // 8
#define CBPC 4               // 32-col blocks per chunk
#define PPB 256              // points per block (512 threads, 8 waves x 32 pts)

typedef __attribute__((ext_vector_type(8))) short short8;
typedef __attribute__((ext_vector_type(16))) float f32x16;

static __device__ __forceinline__ unsigned short f2bf_rne(float f) {
    union { float f; unsigned u; } v; v.f = f;
    unsigned r = v.u + 0x7FFFu + ((v.u >> 16) & 1u);
    return (unsigned short)(r >> 16);
}
static __device__ __forceinline__ float bf2f(unsigned short h) {
    union { unsigned u; float f; } v; v.u = ((unsigned)h) << 16;
    return v.f;
}
static __device__ __forceinline__ bool beats(float sa, int ka, float sb, int kb) {
    return (sa > sb) || (sa == sb && ka < kb);
}
static __device__ __forceinline__ float keyf(float acc, unsigned inv) {
    return __uint_as_float((__float_as_uint(acc) & 0xFFFFFFE0u) | inv);  // v_and_or_b32
}

// prep 1: c2n[k] = 256 - 0.5*||c||^2 (all scores positive -> float cmp == u32 cmp)
__global__ __launch_bounds__(256) void c2n_kernel(const float* __restrict__ cb,
                                                  float* __restrict__ c2n) {
    int k = blockIdx.x * blockDim.x + threadIdx.x;
    if (k >= KCB) return;
    const float4* row = (const float4*)(cb + (size_t)k * DDIM);
    float s0 = 0.f, s1 = 0.f, s2 = 0.f, s3 = 0.f;
#pragma unroll
    for (int j = 0; j < DDIM / 4; ++j) {
        float4 a = row[j];
        s0 = __builtin_fmaf(a.x, a.x, s0);
        s1 = __builtin_fmaf(a.y, a.y, s1);
        s2 = __builtin_fmaf(a.z, a.z, s2);
        s3 = __builtin_fmaf(a.w, a.w, s3);
    }
    c2n[k] = 256.0f - 0.5f * ((s0 + s1) + (s2 + s3));
}

// prep 2: pack codebook into bf16 hi/lo fragment image for 32x32x16 MFMA.
// Col-block cbk (32 codes): 8 KB = ushort[4096]:
//   idx = cbk*4096 + (lo? 2048:0) + ks*512 + kh*256 + col*8 + j
// where code row = cbk*32+col, dim d = ks*16 + kh*8 + j (ks=0..3, kh=0..1).
// B-frag read for lane l (col=l&31, kh=l>>5): byte = cbk*8192 + ks*1024 + l*16 (+4096 lo).
__global__ __launch_bounds__(256) void pack_kernel(const float* __restrict__ cb,
                                                   unsigned short* __restrict__ G) {
    int t = blockIdx.x * 256 + threadIdx.x;  // 8192 threads: (row, d8)
    int r = t >> 3, d8 = t & 7;
    const float4* src = (const float4*)(cb + (size_t)r * DDIM + d8 * 8);
    float4 v0 = src[0], v1 = src[1];
    float vv[8] = {v0.x, v0.y, v0.z, v0.w, v1.x, v1.y, v1.z, v1.w};
    short8 h, l;
#pragma unroll
    for (int j = 0; j < 8; ++j) {
        unsigned short hb = f2bf_rne(vv[j]);
        h[j] = (short)hb;
        l[j] = (short)f2bf_rne(vv[j] - bf2f(hb));
    }
    int cbk = r >> 5, col = r & 31;
    int ks = d8 >> 1, kh = d8 & 1;
    size_t base = (size_t)cbk * 4096 + ks * 512 + kh * 256 + col * 8;  // ushort units
    *(short8*)(G + base) = h;
    *(short8*)(G + base + 2048) = l;
}

__global__ __launch_bounds__(512, 4) void vq_main(const float* __restrict__ x,
                                                  const float* __restrict__ cb,
                                                  const float* __restrict__ c2n,
                                                  const unsigned short* __restrict__ G,
                                                  float* __restrict__ out) {
    __shared__ unsigned short frag[2][CHUNK * DDIM * 2];  // 2 x 32KB double buffer
    __shared__ float lds_c2f[KCB];                        // 4KB acc-init values
    __shared__ int lds_bk1[PPB];
    __shared__ int lds_bk2[PPB];

    const int tid = threadIdx.x;
    const int lane = tid & 63;
    const int wave = tid >> 6;       // 0..7, each owns 32 points
    const int col = lane & 31;       // code column within a 32-col block
    const int kh = lane >> 5;        // k-half selector
    const int blk_base = blockIdx.x * PPB;
    const int wave_base = blk_base + wave * 32;
    const int lane_off = lane * 16;  // byte offset of this lane's B-frag slot

    // ---- A fragments (32x32x16): lane = row(col idx)=lane&31, k = kh*8+j ----
    // Ahi/Alo[ks]: dims d = ks*16 + kh*8 + j. 32 VGPR total, resident.
    short8 Ahi[4], Alo[4];
    {
        const float* xr = x + (size_t)(wave_base + col) * DDIM + kh * 8;
#pragma unroll
        for (int ks = 0; ks < 4; ++ks) {
            float4 v0 = *(const float4*)(xr + ks * 16);
            float4 v1 = *(const float4*)(xr + ks * 16 + 4);
            float vv[8] = {v0.x, v0.y, v0.z, v0.w, v1.x, v1.y, v1.z, v1.w};
            short8 h, l;
#pragma unroll
            for (int j = 0; j < 8; ++j) {
                unsigned short hb = f2bf_rne(vv[j]);
                h[j] = (short)hb;
                l[j] = (short)f2bf_rne(vv[j] - bf2f(hb));
            }
            Ahi[ks] = h;
            Alo[ks] = l;
        }
    }

    // top-2 keys per point (16 rows/lane); positive-float keys, low5 = 31-colblock
    float b1[16], b2[16];
#pragma unroll
    for (int i = 0; i < 16; ++i) { b1[i] = 0.0f; b2[i] = 0.0f; }

    // stage 32KB chunk: 512 threads x 4 x 16B global_load_lds
#define STAGE(cc, buf)                                                                     \
    {                                                                                      \
        const unsigned char* gsrc = (const unsigned char*)G + (size_t)(cc) * 32768 + tid * 16; \
        unsigned char* ldst = (unsigned char*)&frag[buf][0] + tid * 16;                    \
        _Pragma("unroll") for (int it = 0; it < 4; ++it)                                   \
            __builtin_amdgcn_global_load_lds(                                              \
                (const __attribute__((address_space(1))) unsigned int*)(gsrc + it * 8192), \
                (__attribute__((address_space(3))) unsigned int*)(ldst + it * 8192),       \
                16, 0, 0);                                                                 \
    }

    // ---- prologue: stage chunk 0; fill c2n LDS table ----
    STAGE(0, 0);
    lds_c2f[tid] = c2n[tid];
    lds_c2f[tid + 512] = c2n[tid + 512];
    __syncthreads();

    for (int c = 0; c < NCHUNK; ++c) {
        const int cur = c & 1;
        if (c + 1 < NCHUNK) STAGE(c + 1, cur ^ 1);
        const unsigned char* fb = (const unsigned char*)&frag[cur][0];

#pragma unroll
        for (int cbl = 0; cbl < CBPC; ++cbl) {
            const int cbg = c * CBPC + cbl;          // global col-block 0..31
            const unsigned inv = 31u - (unsigned)cbg;
            const unsigned char* pb = fb + cbl * 8192 + lane_off;
            const float cg = lds_c2f[cbg * 32 + col];
            f32x16 cvec;
#pragma unroll
            for (int i = 0; i < 16; ++i) cvec[i] = cg;

            // bf16x3 over K=64: per kstep read (Bhi,Blo), 3 MFMAs into one chain
            f32x16 acc;
            __builtin_amdgcn_s_setprio(1);
#pragma unroll
            for (int ks = 0; ks < 4; ++ks) {
                const short8 Bh = *(const short8*)(pb + ks * 1024);
                const short8 Bl = *(const short8*)(pb + 4096 + ks * 1024);
                acc = __builtin_amdgcn_mfma_f32_32x32x16_bf16(
                    Ahi[ks], Bh, (ks == 0) ? cvec : acc, 0, 0, 0);
                acc = __builtin_amdgcn_mfma_f32_32x32x16_bf16(Ahi[ks], Bl, acc, 0, 0, 0);
                acc = __builtin_amdgcn_mfma_f32_32x32x16_bf16(Alo[ks], Bh, acc, 0, 0, 0);
            }
            __builtin_amdgcn_s_setprio(0);

            // single-insert top-2 per point: b2' = med3(kk,b1,b2); b1' = max(b1,kk)
#pragma unroll
            for (int i = 0; i < 16; ++i) {
                const float kk = keyf(acc[i], inv);
                b2[i] = __builtin_amdgcn_fmed3f(kk, b1[i], b2[i]);
                b1[i] = fmaxf(b1[i], kk);
            }
        }
        __syncthreads();  // next chunk's loads landed under compute; flip buffers
    }
#undef STAGE

    // ---- decode candidate k, merge top-2 across the 32 col-lanes ----
    unsigned int K1[16], K2[16];
    int I1[16], I2[16];
#pragma unroll
    for (int i = 0; i < 16; ++i) {
        K1[i] = __float_as_uint(b1[i]); I1[i] = (int)(31u - (K1[i] & 31u)) * 32 + col;
        K2[i] = __float_as_uint(b2[i]); I2[i] = (int)(31u - (K2[i] & 31u)) * 32 + col;
    }
#pragma unroll
    for (int m = 1; m < 32; m <<= 1) {
#pragma unroll
        for (int i = 0; i < 16; ++i) {
            unsigned int o1 = __shfl_xor(K1[i], m); int oi1 = __shfl_xor(I1[i], m);
            unsigned int o2 = __shfl_xor(K2[i], m); int oi2 = __shfl_xor(I2[i], m);
            bool ob = (o1 > K1[i]) || (o1 == K1[i] && oi1 < I1[i]);
            unsigned int nk1, nk2; int ni1, ni2;
            if (ob) {
                nk1 = o1; ni1 = oi1;
                bool sb = (K1[i] > o2) || (K1[i] == o2 && I1[i] < oi2);
                nk2 = sb ? K1[i] : o2; ni2 = sb ? I1[i] : oi2;
            } else {
                nk1 = K1[i]; ni1 = I1[i];
                bool sb = (o1 > K2[i]) || (o1 == K2[i] && oi1 < I2[i]);
                nk2 = sb ? o1 : K2[i]; ni2 = sb ? oi1 : I2[i];
            }
            K1[i] = nk1; I1[i] = ni1; K2[i] = nk2; I2[i] = ni2;
        }
    }

    if (col == 0) {  // lanes 0 and 32: 16 rows each, row = (i&3)+8*(i>>2)+4*kh
#pragma unroll
        for (int i = 0; i < 16; ++i) {
            int row = (i & 3) + 8 * (i >> 2) + 4 * kh;
            int pl = wave * 32 + row;
            lds_bk1[pl] = I1[i];
            lds_bk2[pl] = I2[i];
        }
    }
    __syncthreads();

    // ---- exact f32 re-rank: 2 threads per point, one candidate each ----
    const int pid = tid >> 1;
    const int p = blk_base + pid;
    const int ksel = (tid & 1) ? lds_bk2[pid] : lds_bk1[pid];
    const float4* xr = (const float4*)(x + (size_t)p * DDIM);
    const float4* cr = (const float4*)(cb + (size_t)ksel * DDIM);
    float da = 0.f, db = 0.f;
#pragma unroll
    for (int j = 0; j < 16; ++j) {
        float4 xv = xr[j];
        float4 u = cr[j];
        da = __builtin_fmaf(xv.x, u.x, da); db = __builtin_fmaf(xv.y, u.y, db);
        da = __builtin_fmaf(xv.z, u.z, da); db = __builtin_fmaf(xv.w, u.w, db);
    }
    float a = (da + db) + c2n[ksel];
    float oa = __shfl_xor(a, 1);
    int ok = __shfl_xor(ksel, 1);
    const bool first = ((tid & 1) == 0);
    float a1 = first ? a : oa; int k1 = first ? ksel : ok;
    float a2 = first ? oa : a; int k2 = first ? ok : ksel;
    int kf = beats(a1, k1, a2, k2) ? k1 : k2;

    if (first) out[p] = (float)kf;
    const float4* cf = (const float4*)(cb + (size_t)kf * DDIM + (tid & 1) * 32);
    float4* qo = (float4*)(out + NPTS + (size_t)p * DDIM + (tid & 1) * 32);
#pragma unroll
    for (int j = 0; j < 8; ++j) qo[j] = cf[j];
}

extern "C" void kernel_launch(void* const* d_in, const int* in_sizes, int n_in,
                              void* d_out, int out_size, void* d_ws, size_t ws_size,
                              hipStream_t stream) {
    const float* x = (const float*)d_in[0];
    const float* cb = (const float*)d_in[1];
    float* c2n = (float*)d_ws;                                      // 4 KB
    unsigned short* G = (unsigned short*)((char*)d_ws + 4096);      // 256 KB image

    hipLaunchKernelGGL(c2n_kernel, dim3(KCB / 256), dim3(256), 0, stream, cb, c2n);
    hipLaunchKernelGGL(pack_kernel, dim3(KCB * 8 / 256), dim3(256), 0, stream, cb, G);
    hipLaunchKernelGGL(vq_main, dim3(NPTS / PPB), dim3(512), 0, stream,
                       x, cb, c2n, G, (float*)d_out);
}